// Round 2
// baseline (350.078 us; speedup 1.0000x reference)
//
#include <hip/hip_runtime.h>

typedef __attribute__((ext_vector_type(8))) short short8;
typedef __attribute__((ext_vector_type(4))) short s4v;
typedef __attribute__((ext_vector_type(4))) float floatx4;

#define SPOS 16384

// round-to-nearest-even fp32 -> bf16 bits
__device__ __forceinline__ unsigned short f2bf(float f) {
    unsigned u = __float_as_uint(f);
    u += 0x7fffu + ((u >> 16) & 1u);
    return (unsigned short)(u >> 16);
}

// Branchless bit-twiddle posit quantizer (verified equivalent of the 128
// sequential where-passes).
__device__ __forceinline__ float posit_q(float x) {
    unsigned xu  = __float_as_uint(x);
    unsigned sgn = xu & 0x80000000u;
    unsigned au  = xu & 0x7fffffffu;
    unsigned m   = au & 0x007fffffu;
    unsigned r   = (au + 0x00080000u) & 0xfff00000u;
    bool bdry = (m & 0x000fffffu) == 0x00080000u;
    unsigned res;
    if (au >= 0x3f800000u) {                      // |x| >= 1
        res = r;
        if (m > 0x00700000u && m < 0x00780000u && au < 0x47700000u)
            res = (au & 0xff800000u) + 0x00800000u;   // -> 2^(E+1)
        if ((bdry && m != 0x00780000u) || au >= 0x47780000u)
            res = au;                              // boundaries & clamp unchanged
    } else {                                       // |x| < 1
        res = (m <= 0x00080000u || m >= 0x00780000u || bdry) ? au : r;
        if (au < 0x37880000u) res = au ? 0x37800000u : 0u;  // -> 2^-16 (0 stays 0)
    }
    return __uint_as_float(sgn | res);
}

// Same, for z >= 0 (post-ReLU) — sign handling dropped, bit-identical result.
__device__ __forceinline__ float posit_q_pos(float z) {
    unsigned au  = __float_as_uint(z);
    unsigned m   = au & 0x007fffffu;
    unsigned r   = (au + 0x00080000u) & 0xfff00000u;
    bool bdry = (m & 0x000fffffu) == 0x00080000u;
    unsigned res;
    if (au >= 0x3f800000u) {
        res = r;
        if (m > 0x00700000u && m < 0x00780000u && au < 0x47700000u)
            res = (au & 0xff800000u) + 0x00800000u;
        if ((bdry && m != 0x00780000u) || au >= 0x47780000u)
            res = au;
    } else {
        res = (m <= 0x00080000u || m >= 0x00780000u || bdry) ? au : r;
        if (au < 0x37880000u) res = au ? 0x37800000u : 0u;
    }
    return __uint_as_float(res);
}

// Quantize weights to bf16 in MFMA-FRAGMENT-PACKED order + fold BN constants.
// Packed layout: i = G*4096 + kb*512 + lane*8 + j  (G=row-group of 16, kb=K-block
// of 32, lane=wave lane, j=0..7) holds W[16G + (lane&15)][32kb + 8*(lane>>4) + j].
__global__ __launch_bounds__(256) void prep_kernel(
    const float* __restrict__ w1, const float* __restrict__ w2,
    const float* __restrict__ b1, const float* __restrict__ g1,
    const float* __restrict__ be1, const float* __restrict__ m1,
    const float* __restrict__ v1,
    const float* __restrict__ b2, const float* __restrict__ g2,
    const float* __restrict__ be2, const float* __restrict__ m2,
    const float* __restrict__ v2,
    unsigned short* __restrict__ w1p, unsigned short* __restrict__ w2p,
    float* __restrict__ cst)
{
    int i = blockIdx.x * 256 + threadIdx.x;
    if (i < 65536) {
        const int j    = i & 7;
        const int lane = (i >> 3) & 63;
        const int kb   = (i >> 9) & 7;
        const int G    = i >> 12;
        const int row  = 16 * G + (lane & 15);
        const int k    = 32 * kb + 8 * (lane >> 4) + j;
        w1p[i] = f2bf(posit_q(w1[row * 256 + k]));
        w2p[i] = f2bf(posit_q(w2[row * 256 + k]));
        if (i < 256) {
            float inv1 = g1[i] / sqrtf(v1[i] + 1e-5f);
            cst[i]       = inv1;
            cst[256 + i] = fmaf(b1[i], inv1, be1[i] - m1[i] * inv1);
            float inv2 = g2[i] / sqrtf(v2[i] + 1e-5f);
            cst[512 + i] = inv2;
            cst[768 + i] = fmaf(b2[i], inv2, be2[i] - m2[i] * inv2);
        }
    }
}

// q layout: 64 rows (p) x 32 column-blocks of 8 bf16, XOR-swizzled:
// block cb stored at physical block (cb ^ (p & 31)) -> all LDS ops bank-minimal.
__device__ __forceinline__ int qidx(int p, int cb) {
    return p * 256 + ((cb ^ (p & 31)) << 3);
}

// One block: 64 positions x all 256 channels; both GEMMs fused through LDS.
// LDS = 32 KB (q) + 8 KB (xs single strip) = 40960 B -> 4 blocks/CU;
// launch_bounds(256,4) caps unified regs at 128/wave so 4 blocks actually fit.
__global__ __launch_bounds__(256, 4) void fused_kernel(
    const float* __restrict__ x,
    const unsigned short* __restrict__ w1p,
    const unsigned short* __restrict__ w2p,
    const float* __restrict__ cst,
    float* __restrict__ out)
{
    __shared__ alignas(16) unsigned short q[64 * 256];  // 32 KB, swizzled
    __shared__ alignas(16) float xs[4 * 512];           // 8 KB, wave-private

    const int b  = blockIdx.x;          // 2048 blocks
    const int n  = b >> 8;
    const int s0 = (b & 255) << 6;
    const float* xb = x   + (size_t)n * (256 * SPOS) + s0;
    float*       ob = out + (size_t)n * (256 * SPOS) + s0;

    const int t    = threadIdx.x;
    const int lane = t & 63;
    const int w    = t >> 6;            // wave id 0..3
    const int quad = lane >> 4;
    const int l15  = lane & 15;

    // ---- Phase 1 (no barriers): wave w owns channels 64w..64w+63.
    // Rolling depth-4 global-load window (32 VGPR), 8 quantize rounds through
    // a single wave-private xs strip (same-wave LDS ops are in-order; no WAR
    // hazard across rounds, RAW within a round handled by lgkmcnt).
    {
        const int g  = lane & 15;       // float4 group along p
        const int co = lane >> 4;       // 0..3
        float* xsw = xs + w * 512;
        const float* src0 = xb + (size_t)(64 * w + co) * SPOS + 4 * g;
        float4 v[8];
        #pragma unroll
        for (int r = 0; r < 4; ++r) {
            v[2 * r]     = *(const float4*)(src0 + (size_t)(8 * r) * SPOS);
            v[2 * r + 1] = *(const float4*)(src0 + (size_t)(8 * r + 4) * SPOS);
        }
        #pragma unroll
        for (int r = 0; r < 8; ++r) {
            float4 a0 = v[2 * (r & 3)];
            float4 a1 = v[2 * (r & 3) + 1];
            if (r < 4) {    // refill the slot for round r+4
                v[2 * (r & 3)]     = *(const float4*)(src0 + (size_t)(8 * (r + 4)) * SPOS);
                v[2 * (r & 3) + 1] = *(const float4*)(src0 + (size_t)(8 * (r + 4) + 4) * SPOS);
            }
            // element p of channel-row cl lives at dword cl*64 + (p ^ 4*cl)
            *(float4*)&xsw[co * 64 + ((4 * g) ^ (4 * co))]             = a0;
            *(float4*)&xsw[(co + 4) * 64 + ((4 * g) ^ (4 * (co + 4)))] = a1;
            short8 pk;
            #pragma unroll
            for (int c8 = 0; c8 < 8; ++c8)
                pk[c8] = (short)f2bf(posit_q(xsw[c8 * 64 + (lane ^ (4 * c8))]));
            *(short8*)&q[qidx(lane, 8 * w + r)] = pk;   // cb = (64w+8r)/8
        }
    }
    __syncthreads();    // q fully populated

    floatx4 acc[4][4];
    #pragma unroll
    for (int i = 0; i < 4; ++i)
        #pragma unroll
        for (int jj = 0; jj < 4; ++jj)
            acc[i][jj] = (floatx4)0.0f;

    // ---- GEMM1: A = W1p (packed, coalesced, L2-hot), B = q ----
    #pragma unroll
    for (int kk = 0; kk < 256; kk += 32) {
        short8 af[4], bf[4];
        #pragma unroll
        for (int i = 0; i < 4; ++i)
            af[i] = *(const short8*)&w1p[(((w * 4 + i) * 8 + (kk >> 5)) * 64 + lane) * 8];
        #pragma unroll
        for (int jj = 0; jj < 4; ++jj)
            bf[jj] = *(const short8*)&q[qidx(16 * jj + l15, (kk >> 3) + quad)];
        #pragma unroll
        for (int i = 0; i < 4; ++i)
            #pragma unroll
            for (int jj = 0; jj < 4; ++jj)
                acc[i][jj] = __builtin_amdgcn_mfma_f32_16x16x32_bf16(af[i], bf[jj], acc[i][jj], 0, 0, 0);
    }

    // Prefetch GEMM2's first af set; L2 latency hides under epilogue-1 VALU.
    short8 af20[4];
    #pragma unroll
    for (int i = 0; i < 4; ++i)
        af20[i] = *(const short8*)&w2p[(((w * 4 + i) * 8 + 0) * 64 + lane) * 8];

    __syncthreads();   // all waves done reading q before overwrite

    const int mbase = w * 64;

    // ---- Epilogue 1: BN1 + ReLU + posit_q -> bf16 back into q[p][m] ----
    {
        const float* sc1 = cst;
        const float* bi1 = cst + 256;
        #pragma unroll
        for (int i = 0; i < 4; ++i) {
            const int m0 = mbase + 16 * i + quad * 4;
            float sc[4], bi[4];
            #pragma unroll
            for (int r = 0; r < 4; ++r) { sc[r] = sc1[m0 + r]; bi[r] = bi1[m0 + r]; }
            #pragma unroll
            for (int jj = 0; jj < 4; ++jj) {
                const int p = 16 * jj + l15;
                s4v h;
                #pragma unroll
                for (int r = 0; r < 4; ++r) {
                    float z = fmaf(acc[i][jj][r], sc[r], bi[r]);
                    z = fmaxf(z, 0.0f);
                    h[r] = (short)f2bf(posit_q_pos(z));
                }
                *(s4v*)&q[qidx(p, m0 >> 3) + (m0 & 7)] = h;
            }
        }
    }
    __syncthreads();

    // ---- GEMM2 (operand-SWAPPED): acc = mfma(q-frag, W2p-frag) so D is
    // transposed: lane holds 4 consecutive POSITIONS of one channel.
    // A/B fragments share the same lane->index mapping, so the swap is free.
    #pragma unroll
    for (int i = 0; i < 4; ++i)
        #pragma unroll
        for (int jj = 0; jj < 4; ++jj)
            acc[i][jj] = (floatx4)0.0f;

    #pragma unroll
    for (int kk = 0; kk < 256; kk += 32) {
        short8 af[4], bf[4];
        #pragma unroll
        for (int i = 0; i < 4; ++i)
            af[i] = (kk == 0) ? af20[i]
                  : *(const short8*)&w2p[(((w * 4 + i) * 8 + (kk >> 5)) * 64 + lane) * 8];
        #pragma unroll
        for (int jj = 0; jj < 4; ++jj)
            bf[jj] = *(const short8*)&q[qidx(16 * jj + l15, (kk >> 3) + quad)];
        #pragma unroll
        for (int i = 0; i < 4; ++i)
            #pragma unroll
            for (int jj = 0; jj < 4; ++jj)
                acc[i][jj] = __builtin_amdgcn_mfma_f32_16x16x32_bf16(bf[jj], af[i], acc[i][jj], 0, 0, 0);
    }

    // ---- Epilogue 2: BN2 + residual + ReLU -> out, fully float4-vectorized.
    // acc[i][jj][r] = out[ch = 64w+16i+l15][pos = s0 + 16jj + 4*quad + r]
    {
        const float* sc2 = cst + 512;
        const float* bi2 = cst + 768;
        #pragma unroll
        for (int i = 0; i < 4; ++i) {
            const int ch = mbase + 16 * i + l15;
            const float sc = sc2[ch];
            const float bi = bi2[ch];
            const float* xr = xb + (size_t)ch * SPOS + 4 * quad;
            float*       orow = ob + (size_t)ch * SPOS + 4 * quad;
            #pragma unroll
            for (int jj = 0; jj < 4; ++jj) {
                float4 res = *(const float4*)(xr + 16 * jj);
                float4 o;
                #pragma unroll
                for (int r = 0; r < 4; ++r) {
                    float v2 = fmaf(acc[i][jj][r], sc, bi) + ((const float*)&res)[r];
                    ((float*)&o)[r] = fmaxf(v2, 0.0f);
                }
                *(float4*)(orow + 16 * jj) = o;
            }
        }
    }
}

extern "C" void kernel_launch(void* const* d_in, const int* in_sizes, int n_in,
                              void* d_out, int out_size, void* d_ws, size_t ws_size,
                              hipStream_t stream) {
    const float* x   = (const float*)d_in[0];
    const float* w1  = (const float*)d_in[1];
    const float* b1  = (const float*)d_in[2];
    const float* g1  = (const float*)d_in[3];
    const float* be1 = (const float*)d_in[4];
    const float* m1  = (const float*)d_in[5];
    const float* v1  = (const float*)d_in[6];
    const float* w2  = (const float*)d_in[7];
    const float* b2  = (const float*)d_in[8];
    const float* g2  = (const float*)d_in[9];
    const float* be2 = (const float*)d_in[10];
    const float* m2  = (const float*)d_in[11];
    const float* v2  = (const float*)d_in[12];

    unsigned short* w1p = (unsigned short*)d_ws;
    unsigned short* w2p = w1p + 65536;
    float* cst = (float*)(w2p + 65536);   // scale1|bias1|scale2|bias2

    prep_kernel<<<256, 256, 0, stream>>>(w1, w2, b1, g1, be1, m1, v1,
                                         b2, g2, be2, m2, v2, w1p, w2p, cst);
    fused_kernel<<<2048, 256, 0, stream>>>(x, w1p, w2p, cst, (float*)d_out);
}

// Round 6
// 340.903 us; speedup vs baseline: 1.0269x; 1.0269x over previous
//
#include <hip/hip_runtime.h>

typedef __attribute__((ext_vector_type(8))) short short8;
typedef __attribute__((ext_vector_type(4))) short s4v;
typedef __attribute__((ext_vector_type(4))) float floatx4;

#define SPOS 16384

// round-to-nearest-even fp32 -> bf16 bits
__device__ __forceinline__ unsigned short f2bf(float f) {
    unsigned u = __float_as_uint(f);
    u += 0x7fffu + ((u >> 16) & 1u);
    return (unsigned short)(u >> 16);
}

// Branchless bit-twiddle posit quantizer (verified equivalent of the 128
// sequential where-passes).
__device__ __forceinline__ float posit_q(float x) {
    unsigned xu  = __float_as_uint(x);
    unsigned sgn = xu & 0x80000000u;
    unsigned au  = xu & 0x7fffffffu;
    unsigned m   = au & 0x007fffffu;
    unsigned r   = (au + 0x00080000u) & 0xfff00000u;
    bool bdry = (m & 0x000fffffu) == 0x00080000u;
    unsigned res;
    if (au >= 0x3f800000u) {                      // |x| >= 1
        res = r;
        if (m > 0x00700000u && m < 0x00780000u && au < 0x47700000u)
            res = (au & 0xff800000u) + 0x00800000u;   // -> 2^(E+1)
        if ((bdry && m != 0x00780000u) || au >= 0x47780000u)
            res = au;                              // boundaries & clamp unchanged
    } else {                                       // |x| < 1
        res = (m <= 0x00080000u || m >= 0x00780000u || bdry) ? au : r;
        if (au < 0x37880000u) res = au ? 0x37800000u : 0u;  // -> 2^-16 (0 stays 0)
    }
    return __uint_as_float(sgn | res);
}

// Same, for z >= 0 (post-ReLU) — sign handling dropped, bit-identical result.
__device__ __forceinline__ float posit_q_pos(float z) {
    unsigned au  = __float_as_uint(z);
    unsigned m   = au & 0x007fffffu;
    unsigned r   = (au + 0x00080000u) & 0xfff00000u;
    bool bdry = (m & 0x000fffffu) == 0x00080000u;
    unsigned res;
    if (au >= 0x3f800000u) {
        res = r;
        if (m > 0x00700000u && m < 0x00780000u && au < 0x47700000u)
            res = (au & 0xff800000u) + 0x00800000u;
        if ((bdry && m != 0x00780000u) || au >= 0x47780000u)
            res = au;
    } else {
        res = (m <= 0x00080000u || m >= 0x00780000u || bdry) ? au : r;
        if (au < 0x37880000u) res = au ? 0x37800000u : 0u;
    }
    return __uint_as_float(res);
}

// Quantize weights to bf16 in MFMA-FRAGMENT-PACKED order + fold BN constants.
// Packed layout: i = G*4096 + kb*512 + lane*8 + j  (G=row-group of 16, kb=K-block
// of 32, lane=wave lane, j=0..7) holds W[16G + (lane&15)][32kb + 8*(lane>>4) + j].
__global__ __launch_bounds__(256) void prep_kernel(
    const float* __restrict__ w1, const float* __restrict__ w2,
    const float* __restrict__ b1, const float* __restrict__ g1,
    const float* __restrict__ be1, const float* __restrict__ m1,
    const float* __restrict__ v1,
    const float* __restrict__ b2, const float* __restrict__ g2,
    const float* __restrict__ be2, const float* __restrict__ m2,
    const float* __restrict__ v2,
    unsigned short* __restrict__ w1p, unsigned short* __restrict__ w2p,
    float* __restrict__ cst)
{
    int i = blockIdx.x * 256 + threadIdx.x;
    if (i < 65536) {
        const int j    = i & 7;
        const int lane = (i >> 3) & 63;
        const int kb   = (i >> 9) & 7;
        const int G    = i >> 12;
        const int row  = 16 * G + (lane & 15);
        const int k    = 32 * kb + 8 * (lane >> 4) + j;
        w1p[i] = f2bf(posit_q(w1[row * 256 + k]));
        w2p[i] = f2bf(posit_q(w2[row * 256 + k]));
        if (i < 256) {
            float inv1 = g1[i] / sqrtf(v1[i] + 1e-5f);
            cst[i]       = inv1;
            cst[256 + i] = fmaf(b1[i], inv1, be1[i] - m1[i] * inv1);
            float inv2 = g2[i] / sqrtf(v2[i] + 1e-5f);
            cst[512 + i] = inv2;
            cst[768 + i] = fmaf(b2[i], inv2, be2[i] - m2[i] * inv2);
        }
    }
}

// q layout: 64 rows (p) x 32 column-blocks of 8 bf16, XOR-swizzled:
// block cb stored at physical block (cb ^ (p & 31)) -> all LDS ops bank-minimal.
__device__ __forceinline__ int qidx(int p, int cb) {
    return p * 256 + ((cb ^ (p & 31)) << 3);
}

// One block: 64 positions x all 256 channels; both GEMMs fused through LDS.
// LDS = 32 KB (q) + 16 KB (xs ping-pong) = 49152 B -> 3 blocks/CU;
// launch_bounds(256,3) gives ~170 unified regs/wave: NO spills (R2's
// (256,4) squeezed arch regs to 64 and spilled to scratch: +42MB WRITE).
__global__ __launch_bounds__(256, 3) void fused_kernel(
    const float* __restrict__ x,
    const unsigned short* __restrict__ w1p,
    const unsigned short* __restrict__ w2p,
    const float* __restrict__ cst,
    float* __restrict__ out)
{
    __shared__ alignas(16) unsigned short q[64 * 256];  // 32 KB, swizzled
    __shared__ alignas(16) float xs[4 * 1024];          // 16 KB, wave-private ping-pong

    const int b  = blockIdx.x;          // 2048 blocks
    const int n  = b >> 8;
    const int s0 = (b & 255) << 6;
    const float* xb = x   + (size_t)n * (256 * SPOS) + s0;
    float*       ob = out + (size_t)n * (256 * SPOS) + s0;

    const int t    = threadIdx.x;
    const int lane = t & 63;
    const int w    = t >> 6;            // wave id 0..3
    const int quad = lane >> 4;
    const int l15  = lane & 15;

    // ---- Phase 1 (no barriers): wave w owns channels 64w..64w+63.
    // All 16 float4 loads issued up front, then 8 quantize rounds through a
    // ping-pong xs strip.
    {
        const int g  = lane & 15;       // float4 group along p
        const int co = lane >> 4;       // 0..3
        float* xsw = xs + w * 1024;
        const float* src0 = xb + (size_t)(64 * w + co) * SPOS + 4 * g;
        floatx4 v[16];
        #pragma unroll
        for (int r = 0; r < 8; ++r) {
            v[2 * r]     = *(const floatx4*)(src0 + (size_t)(8 * r) * SPOS);
            v[2 * r + 1] = *(const floatx4*)(src0 + (size_t)(8 * r + 4) * SPOS);
        }
        #pragma unroll
        for (int r = 0; r < 8; ++r) {
            float* xr = xsw + (r & 1) * 512;
            // element p of channel-row cl lives at dword cl*64 + (p ^ 4*cl)
            *(floatx4*)&xr[co * 64 + ((4 * g) ^ (4 * co))]             = v[2 * r];
            *(floatx4*)&xr[(co + 4) * 64 + ((4 * g) ^ (4 * (co + 4)))] = v[2 * r + 1];
            short8 pk;
            #pragma unroll
            for (int c8 = 0; c8 < 8; ++c8)
                pk[c8] = (short)f2bf(posit_q(xr[c8 * 64 + (lane ^ (4 * c8))]));
            *(short8*)&q[qidx(lane, 8 * w + r)] = pk;   // cb = (64w+8r)/8
        }
    }
    __syncthreads();    // q fully populated

    floatx4 acc[4][4];
    #pragma unroll
    for (int i = 0; i < 4; ++i)
        #pragma unroll
        for (int jj = 0; jj < 4; ++jj)
            acc[i][jj] = (floatx4)0.0f;

    // ---- GEMM1: A = W1p (packed, coalesced, L2-hot), B = q ----
    // Depth-2 af rotation: step kk+1's weight loads issue BEFORE step kk's
    // MFMAs; counted vmcnt waits let L2 latency (~250cy) hide under 16 MFMAs.
    {
        short8 af[2][4], bf[4];
        #pragma unroll
        for (int i = 0; i < 4; ++i)
            af[0][i] = *(const short8*)&w1p[(((w * 4 + i) * 8 + 0) * 64 + lane) * 8];
        #pragma unroll
        for (int kk = 0; kk < 8; ++kk) {
            const int cur = kk & 1, nxt = cur ^ 1;
            if (kk < 7) {
                #pragma unroll
                for (int i = 0; i < 4; ++i)
                    af[nxt][i] = *(const short8*)&w1p[(((w * 4 + i) * 8 + (kk + 1)) * 64 + lane) * 8];
            }
            #pragma unroll
            for (int jj = 0; jj < 4; ++jj)
                bf[jj] = *(const short8*)&q[qidx(16 * jj + l15, 4 * kk + quad)];
            #pragma unroll
            for (int i = 0; i < 4; ++i)
                #pragma unroll
                for (int jj = 0; jj < 4; ++jj)
                    acc[i][jj] = __builtin_amdgcn_mfma_f32_16x16x32_bf16(af[cur][i], bf[jj], acc[i][jj], 0, 0, 0);
        }
    }

    // Prefetch GEMM2's first af set; completes at the barrier drain, lives
    // in regs through epilogue 1.
    short8 af20[4];
    #pragma unroll
    for (int i = 0; i < 4; ++i)
        af20[i] = *(const short8*)&w2p[(((w * 4 + i) * 8 + 0) * 64 + lane) * 8];

    __syncthreads();   // all waves done reading q before overwrite

    const int mbase = w * 64;

    // ---- Epilogue 1: BN1 + ReLU + posit_q -> bf16 back into q[p][m] ----
    {
        const float* sc1 = cst;
        const float* bi1 = cst + 256;
        #pragma unroll
        for (int i = 0; i < 4; ++i) {
            const int m0 = mbase + 16 * i + quad * 4;
            float sc[4], bi[4];
            #pragma unroll
            for (int r = 0; r < 4; ++r) { sc[r] = sc1[m0 + r]; bi[r] = bi1[m0 + r]; }
            #pragma unroll
            for (int jj = 0; jj < 4; ++jj) {
                const int p = 16 * jj + l15;
                s4v h;
                #pragma unroll
                for (int r = 0; r < 4; ++r) {
                    float z = fmaf(acc[i][jj][r], sc[r], bi[r]);
                    z = fmaxf(z, 0.0f);
                    h[r] = (short)f2bf(posit_q_pos(z));
                }
                *(s4v*)&q[qidx(p, m0 >> 3) + (m0 & 7)] = h;
            }
        }
    }
    __syncthreads();

    // ---- GEMM2 (operand-SWAPPED): acc = mfma(q-frag, W2p-frag) so D is
    // transposed: lane holds 4 consecutive POSITIONS of one channel.
    // Same depth-2 af rotation (step 0 was preloaded before epilogue 1).
    #pragma unroll
    for (int i = 0; i < 4; ++i)
        #pragma unroll
        for (int jj = 0; jj < 4; ++jj)
            acc[i][jj] = (floatx4)0.0f;

    {
        short8 af[2][4], bf[4];
        #pragma unroll
        for (int i = 0; i < 4; ++i)
            af[0][i] = af20[i];
        #pragma unroll
        for (int kk = 0; kk < 8; ++kk) {
            const int cur = kk & 1, nxt = cur ^ 1;
            if (kk < 7) {
                #pragma unroll
                for (int i = 0; i < 4; ++i)
                    af[nxt][i] = *(const short8*)&w2p[(((w * 4 + i) * 8 + (kk + 1)) * 64 + lane) * 8];
            }
            #pragma unroll
            for (int jj = 0; jj < 4; ++jj)
                bf[jj] = *(const short8*)&q[qidx(16 * jj + l15, 4 * kk + quad)];
            #pragma unroll
            for (int i = 0; i < 4; ++i)
                #pragma unroll
                for (int jj = 0; jj < 4; ++jj)
                    acc[i][jj] = __builtin_amdgcn_mfma_f32_16x16x32_bf16(bf[jj], af[cur][i], acc[i][jj], 0, 0, 0);
        }
    }

    // ---- Epilogue 2: BN2 + residual + ReLU -> out, float4-vectorized.
    // acc[i][jj][r] = out[ch = 64w+16i+l15][pos = s0 + 16jj + 4*quad + r]
    // All 16 residual loads pre-issued (L3 latency pipelines); nontemporal
    // stores (via ext_vector_type floatx4 — clang builtin rejects HIP float4)
    // keep dead out-lines from evicting x/w from L2.
    {
        const float* sc2 = cst + 512;
        const float* bi2 = cst + 768;
        floatx4 res[4][4];
        #pragma unroll
        for (int i = 0; i < 4; ++i) {
            const int ch = mbase + 16 * i + l15;
            const float* xr = xb + (size_t)ch * SPOS + 4 * quad;
            #pragma unroll
            for (int jj = 0; jj < 4; ++jj)
                res[i][jj] = *(const floatx4*)(xr + 16 * jj);
        }
        #pragma unroll
        for (int i = 0; i < 4; ++i) {
            const int ch = mbase + 16 * i + l15;
            const float sc = sc2[ch];
            const float bi = bi2[ch];
            float* orow = ob + (size_t)ch * SPOS + 4 * quad;
            #pragma unroll
            for (int jj = 0; jj < 4; ++jj) {
                floatx4 o;
                #pragma unroll
                for (int r = 0; r < 4; ++r) {
                    float vv = fmaf(acc[i][jj][r], sc, bi) + res[i][jj][r];
                    o[r] = fmaxf(vv, 0.0f);
                }
                __builtin_nontemporal_store(o, (floatx4*)(orow + 16 * jj));
            }
        }
    }
}

extern "C" void kernel_launch(void* const* d_in, const int* in_sizes, int n_in,
                              void* d_out, int out_size, void* d_ws, size_t ws_size,
                              hipStream_t stream) {
    const float* x   = (const float*)d_in[0];
    const float* w1  = (const float*)d_in[1];
    const float* b1  = (const float*)d_in[2];
    const float* g1  = (const float*)d_in[3];
    const float* be1 = (const float*)d_in[4];
    const float* m1  = (const float*)d_in[5];
    const float* v1  = (const float*)d_in[6];
    const float* w2  = (const float*)d_in[7];
    const float* b2  = (const float*)d_in[8];
    const float* g2  = (const float*)d_in[9];
    const float* be2 = (const float*)d_in[10];
    const float* m2  = (const float*)d_in[11];
    const float* v2  = (const float*)d_in[12];

    unsigned short* w1p = (unsigned short*)d_ws;
    unsigned short* w2p = w1p + 65536;
    float* cst = (float*)(w2p + 65536);   // scale1|bias1|scale2|bias2

    prep_kernel<<<256, 256, 0, stream>>>(w1, w2, b1, g1, be1, m1, v1,
                                         b2, g2, be2, m2, v2, w1p, w2p, cst);
    fused_kernel<<<2048, 256, 0, stream>>>(x, w1p, w2p, cst, (float*)d_out);
}